// Round 6
// baseline (401.624 us; speedup 1.0000x reference)
//
#include <hip/hip_runtime.h>
#include <cfloat>

#define N_PTS 8192
#define DTOK 256
#define KNN 16
#define NCHUNK 32
#define CHUNK 256   // N_PTS / NCHUNK

typedef __attribute__((ext_vector_type(8))) short short8;
typedef __attribute__((ext_vector_type(4))) float float4v;

__device__ inline short f2bf(float f) {   // RTNE fp32 -> bf16
  unsigned u = __float_as_uint(f);
  u += 0x7fffu + ((u >> 16) & 1u);
  return (short)(u >> 16);
}

// ---------------------------------------------------------------------------
// KNN stage 1: deferred-insertion FIFO (as R5) with NCHUNK=32 for 2x waves
// (occupancy was 20%, grid-limited: total threads = N*NCHUNK is structural).
// Output: top-16 j indices per (chunk, point), d ascending -- j only (8 MB),
// the merge recomputes d bit-identically from xyz. Candidate loop unrolled
// x2 with one __any(cnt>=15) drain check per pair (FIFO bounded at 16).
// ---------------------------------------------------------------------------
__global__ __launch_bounds__(256) void knn_partial_kernel(
    const float* __restrict__ xyz, int* __restrict__ part) {
  __shared__ float4 s4[CHUNK];        // x,y,z,sq : 4 KB
  __shared__ uint2 sbuf[KNN][256];    // FIFO [slot][tid] : 32 KB
  const int t = threadIdx.x;
  const int cbase = blockIdx.y * CHUNK;

  {
    int j = cbase + t;
    float x = xyz[3 * j], y = xyz[3 * j + 1], z = xyz[3 * j + 2];
    float sq = __fadd_rn(__fadd_rn(__fmul_rn(x, x), __fmul_rn(y, y)),
                         __fmul_rn(z, z));
    s4[t] = make_float4(x, y, z, sq);
  }
  __syncthreads();

  const int i = blockIdx.x * 256 + t;
  const float xi = xyz[3 * i], yi = xyz[3 * i + 1], zi = xyz[3 * i + 2];
  const float sqi = __fadd_rn(__fadd_rn(__fmul_rn(xi, xi), __fmul_rn(yi, yi)),
                              __fmul_rn(zi, zi));

  float bd[KNN];
  int bx[KNN];
  #pragma unroll
  for (int s = 0; s < KNN; ++s) { bd[s] = FLT_MAX; bx[s] = 0; }
  int cnt = 0;

  auto drain = [&]() {
    int tt = 0;
    while (__any(tt < cnt)) {
      float d = FLT_MAX;
      int j = 0;
      if (tt < cnt) {
        uint2 e = sbuf[tt][t];
        d = __uint_as_float(e.x);
        j = (int)e.y;
      }
      bool c[KNN];
      #pragma unroll
      for (int s = 0; s < KNN; ++s) c[s] = d < bd[s];
      #pragma unroll
      for (int s = KNN - 1; s >= 1; --s) {
        bd[s] = c[s - 1] ? bd[s - 1] : (c[s] ? d : bd[s]);
        bx[s] = c[s - 1] ? bx[s - 1] : (c[s] ? j : bx[s]);
      }
      bd[0] = c[0] ? d : bd[0];
      bx[0] = c[0] ? j : bx[0];
      ++tt;
    }
    cnt = 0;
  };

  for (int jj = 0; jj < CHUNK; jj += 2) {
    #pragma unroll
    for (int u = 0; u < 2; ++u) {
      float4 p = s4[jj + u];
      float dot = fmaf(zi, p.z, fmaf(yi, p.y, __fmul_rn(xi, p.x)));
      float d = __fadd_rn(__fsub_rn(sqi, __fmul_rn(2.0f, dot)), p.w);
      int j = cbase + jj + u;
      if (j == i) d = __fadd_rn(d, 1e10f);
      if (d < bd[KNN - 1]) {
        sbuf[cnt][t] = make_uint2(__float_as_uint(d), (unsigned)j);
        ++cnt;
      }
    }
    if (__any(cnt >= KNN - 1)) drain();
  }
  drain();

  #pragma unroll
  for (int s = 0; s < KNN; ++s)
    part[(size_t)(blockIdx.y * KNN + s) * N_PTS + i] = bx[s];
}

// ---------------------------------------------------------------------------
// KNN stage 2: 32-lane tournament merge of 32 sorted lists per point.
// Distances recomputed from xyz with arithmetic bit-identical to stage 1
// (so cross-list ordering == stage-1 ordering == reference ranking). All 16
// entries per lane prefetched+scored up-front (deep MLP), then 16 rounds of
// butterfly argmin (tie: lowest chunk == lowest j-range) + head advance.
// ---------------------------------------------------------------------------
__global__ __launch_bounds__(256) void knn_merge_kernel(
    const float* __restrict__ xyz, const int* __restrict__ part,
    int* __restrict__ nbr) {
  __shared__ uint2 sl[KNN * 256];     // (d_bits, j) [slot][tid] : 32 KB
  const int t = threadIdx.x;
  const int c = t & 31;               // chunk this lane owns
  const int i = blockIdx.x * 8 + (t >> 5);

  const float xi = xyz[3 * i], yi = xyz[3 * i + 1], zi = xyz[3 * i + 2];
  const float sqi = __fadd_rn(__fadd_rn(__fmul_rn(xi, xi), __fmul_rn(yi, yi)),
                              __fmul_rn(zi, zi));

  float hd = FLT_MAX;  int hj = 0;
  #pragma unroll
  for (int s = 0; s < KNN; ++s) {
    int j = part[(size_t)(c * KNN + s) * N_PTS + i];
    float x = xyz[3 * j], y = xyz[3 * j + 1], z = xyz[3 * j + 2];
    float sq = __fadd_rn(__fadd_rn(__fmul_rn(x, x), __fmul_rn(y, y)),
                         __fmul_rn(z, z));
    float dot = fmaf(zi, z, fmaf(yi, y, __fmul_rn(xi, x)));
    float d = __fadd_rn(__fsub_rn(sqi, __fmul_rn(2.0f, dot)), sq);
    if (s == 0) { hd = d; hj = j; }
    else sl[s * 256 + t] = make_uint2(__float_as_uint(d), (unsigned)j);
  }

  int idx = 1;
  int outj = 0;
  #pragma unroll
  for (int r = 0; r < KNN; ++r) {
    float md = hd;  int mc = c;
    #pragma unroll
    for (int m = 1; m < 32; m <<= 1) {
      float od = __shfl_xor(md, m, 32);
      int oc = __shfl_xor(mc, m, 32);
      bool take = (od < md) || (od == md && oc < mc);
      md = take ? od : md;
      mc = take ? oc : mc;
    }
    int jw = __shfl(hj, mc, 32);      // winner's j, before advance
    if (c == r) outj = jw;            // lane r captures output slot r
    if (c == mc) {                    // winner advances its head
      if (idx < KNN) {
        uint2 e = sl[idx * 256 + t];
        hd = __uint_as_float(e.x);
        hj = (int)e.y;
      } else {
        hd = FLT_MAX;  hj = 0;
      }
      ++idx;
    }
  }
  if (c < KNN) nbr[i * KNN + c] = outj;
}

// ---------------------------------------------------------------------------
// P/Q precompute (unchanged): R = P + b1 - Q, Q.  edge h = relu(R_i + Q_j).
// ---------------------------------------------------------------------------
__global__ __launch_bounds__(256, 4) void pq_kernel(
    const float* __restrict__ main_in, const float* __restrict__ xyz,
    const float* __restrict__ W1, const float* __restrict__ b1,
    float* __restrict__ R, float* __restrict__ Q) {
  const int lane = threadIdx.x & 63;
  const int wave = threadIdx.x >> 6;
  const int ibase = blockIdx.x * 16 + wave * 4;

  float xr[4][5];
  #pragma unroll
  for (int m = 0; m < 4; ++m) {
    int i = ibase + m;
    #pragma unroll
    for (int q = 0; q < 4; ++q) xr[m][q] = main_in[i * DTOK + lane + 64 * q];
    xr[m][4] = (lane < 3) ? xyz[i * 3 + lane] : 0.0f;
  }

  float accP[4][4] = {}, accQ[4][4] = {};

  #pragma unroll
  for (int q = 0; q < 5; ++q) {
    const int lim = (q < 4) ? 64 : 3;
    for (int dl = 0; dl < lim; ++dl) {
      const int d = q * 64 + dl;
      const float* wt = W1 + d * DTOK + lane;
      const float* wb = W1 + (259 + d) * DTOK + lane;
      float a0 = wt[0], a1 = wt[64], a2 = wt[128], a3 = wt[192];
      float c0 = wb[0], c1 = wb[64], c2 = wb[128], c3 = wb[192];
      #pragma unroll
      for (int m = 0; m < 4; ++m) {
        float xv = __uint_as_float(
            __builtin_amdgcn_readlane(__float_as_uint(xr[m][q]), dl));
        accP[m][0] = fmaf(xv, a0, accP[m][0]);
        accP[m][1] = fmaf(xv, a1, accP[m][1]);
        accP[m][2] = fmaf(xv, a2, accP[m][2]);
        accP[m][3] = fmaf(xv, a3, accP[m][3]);
        accQ[m][0] = fmaf(xv, c0, accQ[m][0]);
        accQ[m][1] = fmaf(xv, c1, accQ[m][1]);
        accQ[m][2] = fmaf(xv, c2, accQ[m][2]);
        accQ[m][3] = fmaf(xv, c3, accQ[m][3]);
      }
    }
  }

  #pragma unroll
  for (int m = 0; m < 4; ++m) {
    int i = ibase + m;
    #pragma unroll
    for (int qq = 0; qq < 4; ++qq) {
      int c = lane + 64 * qq;
      R[i * DTOK + c] = (accP[m][qq] + b1[c]) - accQ[m][qq];
      Q[i * DTOK + c] = accQ[m][qq];
    }
  }
}

// ---------------------------------------------------------------------------
// EdgeConv via MFMA (unchanged from R3).
// ---------------------------------------------------------------------------
#define EP 8          // points per group

__global__ __launch_bounds__(256, 2) void edge_mfma_kernel(
    const float* __restrict__ R, const float* __restrict__ Q,
    const int* __restrict__ nbr, const float* __restrict__ W2,
    const float* __restrict__ b2, float* __restrict__ out,
    int num_groups, int groups_per_block) {
  __shared__ short Hs[EP * KNN * DTOK];   // 128 rows x 256, 64 KB
  const int lane = threadIdx.x & 63;
  const int wave = threadIdx.x >> 6;
  const int l15 = lane & 15;
  const int quad = lane >> 4;

  short8 bfr[4][8];
  #pragma unroll
  for (int nt_i = 0; nt_i < 4; ++nt_i) {
    const int n = (wave * 4 + nt_i) * 16 + l15;
    #pragma unroll
    for (int kt = 0; kt < 8; ++kt) {
      short8 f;
      #pragma unroll
      for (int jj = 0; jj < 8; ++jj) {
        int k = kt * 32 + quad * 8 + jj;
        f[jj] = f2bf(W2[k * DTOK + n]);
      }
      bfr[nt_i][kt] = f;
    }
  }

  const int wc8 = lane >> 1;
  const int wsub = (lane & 1) * 4;

  for (int gi = 0; gi < groups_per_block; ++gi) {
    const int g = blockIdx.x + gi * gridDim.x;
    if (g >= num_groups) break;
    const int i0 = g * EP;

    #pragma unroll 4
    for (int rr = 0; rr < 32; ++rr) {
      const int r = wave * 32 + rr;
      const int i = i0 + (r >> 4);
      const int j = nbr[i * KNN + (r & 15)];
      const float4 qj = ((const float4*)(Q + (size_t)j * DTOK))[lane];
      const float4 ri = ((const float4*)(R + (size_t)i * DTOK))[lane];
      uint2 pk;
      pk.x = ((unsigned)(unsigned short)f2bf(fmaxf(ri.x + qj.x, 0.f))) |
             (((unsigned)(unsigned short)f2bf(fmaxf(ri.y + qj.y, 0.f))) << 16);
      pk.y = ((unsigned)(unsigned short)f2bf(fmaxf(ri.z + qj.z, 0.f))) |
             (((unsigned)(unsigned short)f2bf(fmaxf(ri.w + qj.w, 0.f))) << 16);
      *(uint2*)(&Hs[r * DTOK + ((wc8 ^ (r & 7)) << 3) + wsub]) = pk;
    }
    __syncthreads();

    #pragma unroll
    for (int mp = 0; mp < 4; ++mp) {
      float4v acc[2][4];
      #pragma unroll
      for (int mi = 0; mi < 2; ++mi)
        #pragma unroll
        for (int nt_i = 0; nt_i < 4; ++nt_i)
          #pragma unroll
          for (int e = 0; e < 4; ++e) acc[mi][nt_i][e] = 0.f;

      #pragma unroll
      for (int kt = 0; kt < 8; ++kt) {
        const int pc = ((kt * 4 + quad) ^ (l15 & 7)) << 3;
        const short8 a0 = *(const short8*)(
            &Hs[((mp * 2 + 0) * 16 + l15) * DTOK + pc]);
        const short8 a1 = *(const short8*)(
            &Hs[((mp * 2 + 1) * 16 + l15) * DTOK + pc]);
        #pragma unroll
        for (int nt_i = 0; nt_i < 4; ++nt_i) {
          acc[0][nt_i] = __builtin_amdgcn_mfma_f32_16x16x32_bf16(
              a0, bfr[nt_i][kt], acc[0][nt_i], 0, 0, 0);
          acc[1][nt_i] = __builtin_amdgcn_mfma_f32_16x16x32_bf16(
              a1, bfr[nt_i][kt], acc[1][nt_i], 0, 0, 0);
        }
      }

      #pragma unroll
      for (int mi = 0; mi < 2; ++mi) {
        #pragma unroll
        for (int nt_i = 0; nt_i < 4; ++nt_i) {
          float rm = fmaxf(fmaxf(acc[mi][nt_i][0], acc[mi][nt_i][1]),
                           fmaxf(acc[mi][nt_i][2], acc[mi][nt_i][3]));
          rm = fmaxf(rm, __shfl_xor(rm, 16, 64));
          rm = fmaxf(rm, __shfl_xor(rm, 32, 64));
          if (lane < 16) {
            const int i = i0 + mp * 2 + mi;
            const int n = (wave * 4 + nt_i) * 16 + lane;
            out[(size_t)i * DTOK + n] = rm + b2[n];
          }
        }
      }
    }
    __syncthreads();
  }
}

// ---------------------------------------------------------------------------
extern "C" void kernel_launch(void* const* d_in, const int* in_sizes, int n_in,
                              void* d_out, int out_size, void* d_ws,
                              size_t ws_size, hipStream_t stream) {
  const float* xyz = (const float*)d_in[0];
  const float* feat = (const float*)d_in[1];
  const float* W1a = (const float*)d_in[2];
  const float* b1a = (const float*)d_in[3];
  const float* W2a = (const float*)d_in[4];
  const float* b2a = (const float*)d_in[5];
  const float* W1b = (const float*)d_in[6];
  const float* b1b = (const float*)d_in[7];
  const float* W2b = (const float*)d_in[8];
  const float* b2b = (const float*)d_in[9];
  float* out = (float*)d_out;

  char* w = (char*)d_ws;
  const size_t SZ_NBR = (size_t)N_PTS * KNN * sizeof(int);        // 512 KB
  const size_t SZ_MAT = (size_t)N_PTS * DTOK * sizeof(float);     // 8 MB
  int* nbr = (int*)w;
  int* part = (int*)(w + SZ_NBR);              // 16 MB (spans bufA+bufB)
  float* bufA = (float*)(w + SZ_NBR);          // later: R
  float* bufB = (float*)(w + SZ_NBR + SZ_MAT); // later: Q
  float* bufC = (float*)(w + SZ_NBR + 2 * SZ_MAT);

  knn_partial_kernel<<<dim3(N_PTS / 256, NCHUNK), 256, 0, stream>>>(xyz, part);
  knn_merge_kernel<<<N_PTS / 8, 256, 0, stream>>>(xyz, part, nbr);

  const int num_groups = N_PTS / EP;           // 1024
  const int nblocks = 512;                     // 2 groups/block

  // layer a
  pq_kernel<<<N_PTS / 16, 256, 0, stream>>>(feat, xyz, W1a, b1a, bufA, bufB);
  edge_mfma_kernel<<<nblocks, 256, 0, stream>>>(bufA, bufB, nbr, W2a, b2a,
                                                bufC, num_groups, 2);

  // layer b
  pq_kernel<<<N_PTS / 16, 256, 0, stream>>>(bufC, xyz, W1b, b1b, bufA, bufB);
  edge_mfma_kernel<<<nblocks, 256, 0, stream>>>(bufA, bufB, nbr, W2b, b2b,
                                                out, num_groups, 2);
}

// Round 7
// 333.262 us; speedup vs baseline: 1.2051x; 1.2051x over previous
//
#include <hip/hip_runtime.h>
#include <cfloat>

#define N_PTS 8192
#define DTOK 256
#define KNN 16
#define NCHUNK 16
#define CHUNK 512   // N_PTS / NCHUNK

typedef __attribute__((ext_vector_type(8))) short short8;
typedef __attribute__((ext_vector_type(4))) float float4v;

__device__ inline short f2bf(float f) {   // RTNE fp32 -> bf16
  unsigned u = __float_as_uint(f);
  u += 0x7fffu + ((u >> 16) & 1u);
  return (short)(u >> 16);
}
__device__ inline float bf2f(short h) {
  return __uint_as_float(((unsigned)(unsigned short)h) << 16);
}

// ---------------------------------------------------------------------------
// KNN stage 1 (R5 config: NCHUNK=16, deferred-insertion FIFO, packed uint2).
// ---------------------------------------------------------------------------
__global__ __launch_bounds__(256) void knn_partial_kernel(
    const float* __restrict__ xyz, uint2* __restrict__ part) {
  __shared__ float4 s4[CHUNK];        // x,y,z,sq : 8 KB
  __shared__ uint2 sbuf[KNN][256];    // FIFO [slot][tid] : 32 KB
  const int t = threadIdx.x;
  const int cbase = blockIdx.y * CHUNK;

  #pragma unroll
  for (int r = 0; r < CHUNK / 256; ++r) {
    int jj = t + 256 * r;
    int j = cbase + jj;
    float x = xyz[3 * j], y = xyz[3 * j + 1], z = xyz[3 * j + 2];
    float sq = __fadd_rn(__fadd_rn(__fmul_rn(x, x), __fmul_rn(y, y)),
                         __fmul_rn(z, z));
    s4[jj] = make_float4(x, y, z, sq);
  }
  __syncthreads();

  const int i = blockIdx.x * 256 + t;
  const float xi = xyz[3 * i], yi = xyz[3 * i + 1], zi = xyz[3 * i + 2];
  const float sqi = __fadd_rn(__fadd_rn(__fmul_rn(xi, xi), __fmul_rn(yi, yi)),
                              __fmul_rn(zi, zi));

  float bd[KNN];
  int bx[KNN];
  #pragma unroll
  for (int s = 0; s < KNN; ++s) { bd[s] = FLT_MAX; bx[s] = 0; }
  int cnt = 0;

  auto drain = [&]() {
    int tt = 0;
    while (__any(tt < cnt)) {
      float d = FLT_MAX;
      int j = 0;
      if (tt < cnt) {
        uint2 e = sbuf[tt][t];
        d = __uint_as_float(e.x);
        j = (int)e.y;
      }
      bool c[KNN];
      #pragma unroll
      for (int s = 0; s < KNN; ++s) c[s] = d < bd[s];
      #pragma unroll
      for (int s = KNN - 1; s >= 1; --s) {
        bd[s] = c[s - 1] ? bd[s - 1] : (c[s] ? d : bd[s]);
        bx[s] = c[s - 1] ? bx[s - 1] : (c[s] ? j : bx[s]);
      }
      bd[0] = c[0] ? d : bd[0];
      bx[0] = c[0] ? j : bx[0];
      ++tt;
    }
    cnt = 0;
  };

  for (int jj = 0; jj < CHUNK; ++jj) {
    float4 p = s4[jj];
    float dot = fmaf(zi, p.z, fmaf(yi, p.y, __fmul_rn(xi, p.x)));
    float d = __fadd_rn(__fsub_rn(sqi, __fmul_rn(2.0f, dot)), p.w);
    int j = cbase + jj;
    if (j == i) d = __fadd_rn(d, 1e10f);
    if (d < bd[KNN - 1]) {
      sbuf[cnt][t] = make_uint2(__float_as_uint(d), (unsigned)j);
      ++cnt;
    }
    if (__any(cnt == KNN)) drain();
  }
  drain();

  #pragma unroll
  for (int s = 0; s < KNN; ++s) {
    int slot = blockIdx.y * KNN + s;
    part[(size_t)slot * N_PTS + i] =
        make_uint2(__float_as_uint(bd[s]), (unsigned)bx[s]);
  }
}

// ---------------------------------------------------------------------------
// KNN stage 2 (R5: 16-lane tournament merge).
// ---------------------------------------------------------------------------
__global__ __launch_bounds__(256) void knn_merge_kernel(
    const uint2* __restrict__ part, int* __restrict__ nbr) {
  __shared__ uint2 sl[KNN * 256];     // [slot][tid] : 32 KB
  const int t = threadIdx.x;
  const int c = t & 15;               // chunk this lane owns
  const int i = blockIdx.x * 16 + (t >> 4);

  float hd;  int hj;
  {
    uint2 e0 = part[(size_t)(c * KNN) * N_PTS + i];
    hd = __uint_as_float(e0.x);
    hj = (int)e0.y;
    #pragma unroll
    for (int s = 1; s < KNN; ++s)
      sl[s * 256 + t] = part[(size_t)(c * KNN + s) * N_PTS + i];
  }

  int idx = 1;
  int outj = 0;
  #pragma unroll
  for (int r = 0; r < KNN; ++r) {
    float md = hd;  int mc = c;
    #pragma unroll
    for (int m = 1; m < 16; m <<= 1) {
      float od = __shfl_xor(md, m, 16);
      int oc = __shfl_xor(mc, m, 16);
      bool take = (od < md) || (od == md && oc < mc);
      md = take ? od : md;
      mc = take ? oc : mc;
    }
    int jw = __shfl(hj, mc, 16);
    if (c == r) outj = jw;
    if (c == mc) {
      if (idx < KNN) {
        uint2 e = sl[idx * 256 + t];
        hd = __uint_as_float(e.x);
        hj = (int)e.y;
      } else {
        hd = FLT_MAX;  hj = 0;
      }
      ++idx;
    }
  }
  nbr[i * KNN + c] = outj;
}

// ---------------------------------------------------------------------------
// Split-precision prep: X -> Ahi + Alo (bf16), residual-split so that
// Ahi@Bhi + Ahi@Blo + Alo@Bhi reproduces fp32 X@B to ~1e-4 abs.
// ---------------------------------------------------------------------------
__global__ __launch_bounds__(256) void convert_a_kernel(
    const float* __restrict__ src, short* __restrict__ hi,
    short* __restrict__ lo) {
  const int idx = (blockIdx.x * 256 + threadIdx.x) * 4;
  const float4 v = *(const float4*)(src + idx);
  short h0 = f2bf(v.x), h1 = f2bf(v.y), h2 = f2bf(v.z), h3 = f2bf(v.w);
  short l0 = f2bf(v.x - bf2f(h0)), l1 = f2bf(v.y - bf2f(h1));
  short l2 = f2bf(v.z - bf2f(h2)), l3 = f2bf(v.w - bf2f(h3));
  *(uint2*)(hi + idx) = make_uint2(
      ((unsigned)(unsigned short)h0) | (((unsigned)(unsigned short)h1) << 16),
      ((unsigned)(unsigned short)h2) | (((unsigned)(unsigned short)h3) << 16));
  *(uint2*)(lo + idx) = make_uint2(
      ((unsigned)(unsigned short)l0) | (((unsigned)(unsigned short)l1) << 16),
      ((unsigned)(unsigned short)l2) | (((unsigned)(unsigned short)l3) << 16));
}

// ---------------------------------------------------------------------------
// W1 -> Bt (transposed, n-major): Bt[n][k]; n<256: P-part = W1[k][n];
// n>=256: Q-part = W1[259+k][n-256]. Feat rows only (xyz rows 256..258 /
// 515..517 handled in the GEMM epilogue in fp32).
// ---------------------------------------------------------------------------
__global__ __launch_bounds__(256) void convert_w_kernel(
    const float* __restrict__ W1, short* __restrict__ bhi,
    short* __restrict__ blo) {
  const int n = blockIdx.x;      // 0..511
  const int k = threadIdx.x;     // 0..255
  const float v = (n < 256) ? W1[k * DTOK + n]
                            : W1[(259 + k) * DTOK + (n - 256)];
  short h = f2bf(v);
  bhi[n * 256 + k] = h;
  blo[n * 256 + k] = f2bf(v - bf2f(h));
}

// ---------------------------------------------------------------------------
// pq GEMM: C(8192x512) = Ahi@Bhi + Ahi@Blo + Alo@Bhi (fp32 acc), where
// cols 0..255 = P, 256..511 = Q. Block: M-tile 128 x (64 P-cols + the
// MATCHING 64 Q-cols) so the epilogue can form R = P + b1 + xyzP - Qfull
// and Q = Qacc + xyzQ in-block. Waves: w&1 = m-half, w>>1 = P/Q strip.
// Frag conventions identical to the verified edge kernel (16x16x32 bf16).
// 64B LDS tile strides are bank-uniform for b128 frag reads (no swizzle).
// ---------------------------------------------------------------------------
__global__ __launch_bounds__(256, 1) void pq_gemm_kernel(
    const short* __restrict__ Ahi, const short* __restrict__ Alo,
    const short* __restrict__ Bthi, const short* __restrict__ Btlo,
    const float* __restrict__ xyz, const float* __restrict__ W1,
    const float* __restrict__ b1, float* __restrict__ R,
    float* __restrict__ Q) {
  __shared__ char smem[33280];                 // K-loop: As+Bs (16KB) | epi: Qs
  __shared__ float sx[128][3];                 // xyz rows of this M-tile
  __shared__ float swz[6][64];                 // W1 xyz rows (P:0..2, Q:3..5)
  __shared__ float sb1[64];
  short (*As)[32] = (short(*)[32])smem;        // 128 x 32 bf16
  short (*Bs)[32] = (short(*)[32])(smem + 8192);
  float (*Qs)[65] = (float(*)[65])smem;        // 128 x 65 fp32 (epilogue)

  const int tid = threadIdx.x;
  const int lane = tid & 63;
  const int wave = tid >> 6;
  const int l15 = lane & 15;
  const int quad = lane >> 4;
  const int mh = wave & 1;                     // m-half (0: rows 0-63)
  const int qh = wave >> 1;                    // 0: P strip, 1: Q strip
  const int m0 = blockIdx.x * 128;
  const int np0 = blockIdx.y * 64;

  if (tid < 128) {
    sx[tid][0] = xyz[(m0 + tid) * 3];
    sx[tid][1] = xyz[(m0 + tid) * 3 + 1];
    sx[tid][2] = xyz[(m0 + tid) * 3 + 2];
  } else if (tid < 192) {
    int n = tid - 128;
    sb1[n] = b1[np0 + n];
    #pragma unroll
    for (int r = 0; r < 3; ++r) {
      swz[r][n] = W1[(256 + r) * DTOK + np0 + n];
      swz[3 + r][n] = W1[(515 + r) * DTOK + np0 + n];
    }
  }

  float4v acc[4][4];
  #pragma unroll
  for (int mf = 0; mf < 4; ++mf)
    #pragma unroll
    for (int nf = 0; nf < 4; ++nf)
      #pragma unroll
      for (int e = 0; e < 4; ++e) acc[mf][nf][e] = 0.f;

  const int sr = tid >> 2;                     // staging row 0..63
  const int sq = (tid & 3) * 8;                // staging col (bf16 elems)

  #pragma unroll 1
  for (int pass = 0; pass < 3; ++pass) {
    const short* Asrc = (pass == 2) ? Alo : Ahi;
    const short* Bsrc = (pass == 1) ? Btlo : Bthi;
    #pragma unroll 1
    for (int kc = 0; kc < 8; ++kc) {
      const int k0 = kc * 32;
      __syncthreads();
      *(uint4*)(&As[sr][sq]) =
          *(const uint4*)(Asrc + (size_t)(m0 + sr) * 256 + k0 + sq);
      *(uint4*)(&As[sr + 64][sq]) =
          *(const uint4*)(Asrc + (size_t)(m0 + sr + 64) * 256 + k0 + sq);
      *(uint4*)(&Bs[sr][sq]) =
          *(const uint4*)(Bsrc + (size_t)(np0 + sr) * 256 + k0 + sq);
      *(uint4*)(&Bs[sr + 64][sq]) =
          *(const uint4*)(Bsrc + (size_t)(256 + np0 + sr) * 256 + k0 + sq);
      __syncthreads();

      short8 af[4], bf[4];
      #pragma unroll
      for (int mf = 0; mf < 4; ++mf)
        af[mf] = *(const short8*)(&As[mh * 64 + mf * 16 + l15][quad * 8]);
      #pragma unroll
      for (int nf = 0; nf < 4; ++nf)
        bf[nf] = *(const short8*)(&Bs[qh * 64 + nf * 16 + l15][quad * 8]);
      #pragma unroll
      for (int mf = 0; mf < 4; ++mf)
        #pragma unroll
        for (int nf = 0; nf < 4; ++nf)
          acc[mf][nf] = __builtin_amdgcn_mfma_f32_16x16x32_bf16(
              af[mf], bf[nf], acc[mf][nf], 0, 0, 0);
    }
  }

  // ---- epilogue ----
  __syncthreads();                             // As/Bs dead; Qs aliases smem
  if (qh == 1) {                               // Q waves: finish Q, share it
    #pragma unroll
    for (int mf = 0; mf < 4; ++mf)
      #pragma unroll
      for (int nf = 0; nf < 4; ++nf)
        #pragma unroll
        for (int e = 0; e < 4; ++e) {
          int row = mh * 64 + mf * 16 + quad * 4 + e;
          int col = nf * 16 + l15;
          float q = acc[mf][nf][e] + sx[row][0] * swz[3][col] +
                    sx[row][1] * swz[4][col] + sx[row][2] * swz[5][col];
          Qs[row][col] = q;
          Q[(size_t)(m0 + row) * DTOK + np0 + col] = q;
        }
  }
  __syncthreads();
  if (qh == 0) {                               // P waves: R = P + b1 - Qfull
    #pragma unroll
    for (int mf = 0; mf < 4; ++mf)
      #pragma unroll
      for (int nf = 0; nf < 4; ++nf)
        #pragma unroll
        for (int e = 0; e < 4; ++e) {
          int row = mh * 64 + mf * 16 + quad * 4 + e;
          int col = nf * 16 + l15;
          float p = acc[mf][nf][e] + sx[row][0] * swz[0][col] +
                    sx[row][1] * swz[1][col] + sx[row][2] * swz[2][col];
          R[(size_t)(m0 + row) * DTOK + np0 + col] =
              (p + sb1[col]) - Qs[row][col];
        }
  }
}

// ---------------------------------------------------------------------------
// EdgeConv via MFMA (unchanged from R3).
// ---------------------------------------------------------------------------
#define EP 8          // points per group

__global__ __launch_bounds__(256, 2) void edge_mfma_kernel(
    const float* __restrict__ R, const float* __restrict__ Q,
    const int* __restrict__ nbr, const float* __restrict__ W2,
    const float* __restrict__ b2, float* __restrict__ out,
    int num_groups, int groups_per_block) {
  __shared__ short Hs[EP * KNN * DTOK];   // 128 rows x 256, 64 KB
  const int lane = threadIdx.x & 63;
  const int wave = threadIdx.x >> 6;
  const int l15 = lane & 15;
  const int quad = lane >> 4;

  short8 bfr[4][8];
  #pragma unroll
  for (int nt_i = 0; nt_i < 4; ++nt_i) {
    const int n = (wave * 4 + nt_i) * 16 + l15;
    #pragma unroll
    for (int kt = 0; kt < 8; ++kt) {
      short8 f;
      #pragma unroll
      for (int jj = 0; jj < 8; ++jj) {
        int k = kt * 32 + quad * 8 + jj;
        f[jj] = f2bf(W2[k * DTOK + n]);
      }
      bfr[nt_i][kt] = f;
    }
  }

  const int wc8 = lane >> 1;
  const int wsub = (lane & 1) * 4;

  for (int gi = 0; gi < groups_per_block; ++gi) {
    const int g = blockIdx.x + gi * gridDim.x;
    if (g >= num_groups) break;
    const int i0 = g * EP;

    #pragma unroll 4
    for (int rr = 0; rr < 32; ++rr) {
      const int r = wave * 32 + rr;
      const int i = i0 + (r >> 4);
      const int j = nbr[i * KNN + (r & 15)];
      const float4 qj = ((const float4*)(Q + (size_t)j * DTOK))[lane];
      const float4 ri = ((const float4*)(R + (size_t)i * DTOK))[lane];
      uint2 pk;
      pk.x = ((unsigned)(unsigned short)f2bf(fmaxf(ri.x + qj.x, 0.f))) |
             (((unsigned)(unsigned short)f2bf(fmaxf(ri.y + qj.y, 0.f))) << 16);
      pk.y = ((unsigned)(unsigned short)f2bf(fmaxf(ri.z + qj.z, 0.f))) |
             (((unsigned)(unsigned short)f2bf(fmaxf(ri.w + qj.w, 0.f))) << 16);
      *(uint2*)(&Hs[r * DTOK + ((wc8 ^ (r & 7)) << 3) + wsub]) = pk;
    }
    __syncthreads();

    #pragma unroll
    for (int mp = 0; mp < 4; ++mp) {
      float4v acc[2][4];
      #pragma unroll
      for (int mi = 0; mi < 2; ++mi)
        #pragma unroll
        for (int nt_i = 0; nt_i < 4; ++nt_i)
          #pragma unroll
          for (int e = 0; e < 4; ++e) acc[mi][nt_i][e] = 0.f;

      #pragma unroll
      for (int kt = 0; kt < 8; ++kt) {
        const int pc = ((kt * 4 + quad) ^ (l15 & 7)) << 3;
        const short8 a0 = *(const short8*)(
            &Hs[((mp * 2 + 0) * 16 + l15) * DTOK + pc]);
        const short8 a1 = *(const short8*)(
            &Hs[((mp * 2 + 1) * 16 + l15) * DTOK + pc]);
        #pragma unroll
        for (int nt_i = 0; nt_i < 4; ++nt_i) {
          acc[0][nt_i] = __builtin_amdgcn_mfma_f32_16x16x32_bf16(
              a0, bfr[nt_i][kt], acc[0][nt_i], 0, 0, 0);
          acc[1][nt_i] = __builtin_amdgcn_mfma_f32_16x16x32_bf16(
              a1, bfr[nt_i][kt], acc[1][nt_i], 0, 0, 0);
        }
      }

      #pragma unroll
      for (int mi = 0; mi < 2; ++mi) {
        #pragma unroll
        for (int nt_i = 0; nt_i < 4; ++nt_i) {
          float rm = fmaxf(fmaxf(acc[mi][nt_i][0], acc[mi][nt_i][1]),
                           fmaxf(acc[mi][nt_i][2], acc[mi][nt_i][3]));
          rm = fmaxf(rm, __shfl_xor(rm, 16, 64));
          rm = fmaxf(rm, __shfl_xor(rm, 32, 64));
          if (lane < 16) {
            const int i = i0 + mp * 2 + mi;
            const int n = (wave * 4 + nt_i) * 16 + lane;
            out[(size_t)i * DTOK + n] = rm + b2[n];
          }
        }
      }
    }
    __syncthreads();
  }
}

// ---------------------------------------------------------------------------
extern "C" void kernel_launch(void* const* d_in, const int* in_sizes, int n_in,
                              void* d_out, int out_size, void* d_ws,
                              size_t ws_size, hipStream_t stream) {
  const float* xyz = (const float*)d_in[0];
  const float* feat = (const float*)d_in[1];
  const float* W1a = (const float*)d_in[2];
  const float* b1a = (const float*)d_in[3];
  const float* W2a = (const float*)d_in[4];
  const float* b2a = (const float*)d_in[5];
  const float* W1b = (const float*)d_in[6];
  const float* b1b = (const float*)d_in[7];
  const float* W2b = (const float*)d_in[8];
  const float* b2b = (const float*)d_in[9];
  float* out = (float*)d_out;

  // ws layout (25 MB): nbr 0.5 | 16MB region (knn: part / later: Ahi,Alo,R)
  //                    | Q 8MB | Bt hi/lo 0.5MB.  bufC lives in d_out.
  char* w = (char*)d_ws;
  const size_t SZ_NBR = (size_t)N_PTS * KNN * sizeof(int);        // 512 KB
  const size_t MB = 1024 * 1024;
  int* nbr = (int*)w;
  char* w1 = w + SZ_NBR;
  uint2* part = (uint2*)w1;                    // knn phase (16 MB)
  short* Ahi = (short*)w1;                     // 4 MB
  short* Alo = (short*)(w1 + 4 * MB);          // 4 MB
  float* R = (float*)(w1 + 8 * MB);            // 8 MB
  float* Q = (float*)(w + SZ_NBR + 16 * MB);   // 8 MB
  short* Bthi = (short*)(w + SZ_NBR + 24 * MB);// 256 KB
  short* Btlo = Bthi + 512 * 256;              // 256 KB
  float* bufC = out;                           // layer-a output staging

  knn_partial_kernel<<<dim3(N_PTS / 256, NCHUNK), 256, 0, stream>>>(xyz, part);
  knn_merge_kernel<<<N_PTS / 16, 256, 0, stream>>>(part, nbr);

  const int num_groups = N_PTS / EP;           // 1024
  const int nblocks = 512;

  // layer a
  convert_w_kernel<<<512, 256, 0, stream>>>(W1a, Bthi, Btlo);
  convert_a_kernel<<<N_PTS * DTOK / 1024, 256, 0, stream>>>(feat, Ahi, Alo);
  pq_gemm_kernel<<<dim3(N_PTS / 128, 4), 256, 0, stream>>>(
      Ahi, Alo, Bthi, Btlo, xyz, W1a, b1a, R, Q);
  edge_mfma_kernel<<<nblocks, 256, 0, stream>>>(R, Q, nbr, W2a, b2a, bufC,
                                                num_groups, 2);

  // layer b
  convert_w_kernel<<<512, 256, 0, stream>>>(W1b, Bthi, Btlo);
  convert_a_kernel<<<N_PTS * DTOK / 1024, 256, 0, stream>>>(bufC, Ahi, Alo);
  pq_gemm_kernel<<<dim3(N_PTS / 128, 4), 256, 0, stream>>>(
      Ahi, Alo, Bthi, Btlo, xyz, W1b, b1b, R, Q);
  edge_mfma_kernel<<<nblocks, 256, 0, stream>>>(R, Q, nbr, W2b, b2b, out,
                                                num_groups, 2);
}